// Round 5
// baseline (164.587 us; speedup 1.0000x reference)
//
#include <hip/hip_runtime.h>

// CRF NLL, 3-kernel pipeline. B=1024, T=2048, K=9 (START=7, STOP=8).
// A (chunk):   1 wave/block, 8 lane-groups x 8 lanes = 8 chunks; per-group
//              7x7 linear-space transfer matrix over L=64 steps.
//              E in SGPRs; depth-2 load pipeline (B0/B1/B2 rotation) with
//              __launch_bounds__(64,3) so the compiler KEEPS the pipeline.
// B (combine): 1 block/sentence; gold score + tree-fold of 32 log-matrices
//              (5 rounds x 4 parallel 7x7 log-matmuls) + START/STOP closure.
// C (reduce):  mean over 1024 per-sentence NLLs.

#define START_TAG 7
#define STOP_TAG  8
#define KD     9
#define NS     7
#define CHUNKS 32
#define SLOT   56          // stored floats per chunk matrix: [i:7][j:8]
#define NEG1   (-1e30f)

__device__ __forceinline__ float rfl(float x) {
    return __int_as_float(__builtin_amdgcn_readfirstlane(__float_as_int(x)));
}

// ---------------- Kernel A: chunk transfer matrices ----------------
__global__ __launch_bounds__(64, 3) void crf_chunkA(
    const float* __restrict__ feats,
    const float* __restrict__ trans,
    const int*   __restrict__ lengths,
    float* __restrict__ logM,
    int T, int L)
{
    // E = exp(trans[0..6][0..6]) -> SGPRs (uniform). Before any divergent exit.
    float E[49];
    #pragma unroll
    for (int k = 0; k < 49; ++k)
        E[k] = rfl(__expf(trans[(k / 7) * KD + (k % 7)]));

    const int gtid  = blockIdx.x * 64 + threadIdx.x;
    const int lane8 = gtid & 7;
    const int grp   = gtid >> 3;          // b*CHUNKS + c
    const int c     = grp & (CHUNKS - 1);
    const int b     = grp >> 5;

    const int len    = lengths[b];
    const int t0     = c * L;
    const int tstart = (t0 > 1) ? t0 : 1; // t=0 handled in combine
    const int tend   = min(t0 + L, len);
    const int n      = tend - tstart;
    if (lane8 >= NS || n <= 0) return;

    const float* fp = feats + ((size_t)b * T + tstart) * KD;

    float p[NS];
    #pragma unroll
    for (int j = 0; j < NS; ++j) p[j] = (j == lane8) ? 1.f : 0.f;
    float s = 0.f;

    const int mb   = n >> 2;
    const int tail = n & 3;
    const int nm1  = n - 1;

    float4 B0[8], B1[8], B2[8];

    #define LOADB(DST, M) do {                                                  \
        int r0_ = min(4*(M)+0, nm1), r1_ = min(4*(M)+1, nm1);                   \
        int r2_ = min(4*(M)+2, nm1), r3_ = min(4*(M)+3, nm1);                   \
        DST[0] = *(const float4*)(fp + r0_*KD); DST[1] = *(const float4*)(fp + r0_*KD + 4); \
        DST[2] = *(const float4*)(fp + r1_*KD); DST[3] = *(const float4*)(fp + r1_*KD + 4); \
        DST[4] = *(const float4*)(fp + r2_*KD); DST[5] = *(const float4*)(fp + r2_*KD + 4); \
        DST[6] = *(const float4*)(fp + r3_*KD); DST[7] = *(const float4*)(fp + r3_*KD + 4); \
    } while (0)

    #define STEP(FA, FB) do {                                                   \
        float ef[NS] = { __expf((FA).x), __expf((FA).y), __expf((FA).z),        \
                         __expf((FA).w), __expf((FB).x), __expf((FB).y),        \
                         __expf((FB).z) };                                      \
        float q[NS];                                                            \
        _Pragma("unroll")                                                       \
        for (int j = 0; j < NS; ++j) {                                          \
            float acc = E[j*7] * p[0];                                          \
            _Pragma("unroll")                                                   \
            for (int i = 1; i < NS; ++i) acc = fmaf(E[j*7+i], p[i], acc);       \
            q[j] = acc;                                                         \
        }                                                                       \
        _Pragma("unroll")                                                       \
        for (int j = 0; j < NS; ++j) p[j] = q[j] * ef[j];                       \
    } while (0)

    #define RENORM() do {                                                       \
        float m = p[0];                                                         \
        _Pragma("unroll")                                                       \
        for (int j = 1; j < NS; ++j) m = fmaxf(m, p[j]);                        \
        float rm = __builtin_amdgcn_rcpf(m);                                    \
        _Pragma("unroll")                                                       \
        for (int j = 0; j < NS; ++j) p[j] *= rm;                                \
        s += __logf(m);                                                         \
    } while (0)

    LOADB(B0, 0);
    LOADB(B1, 1);

    for (int m = 0; m < mb; ++m) {
        LOADB(B2, m + 2);                 // clamped; consumed 2 iterations later
        STEP(B0[0], B0[1]); STEP(B0[2], B0[3]);
        STEP(B0[4], B0[5]); STEP(B0[6], B0[7]);
        RENORM();
        #pragma unroll
        for (int k = 0; k < 8; ++k) { B0[k] = B1[k]; B1[k] = B2[k]; }
    }
    if (tail > 0) {
        STEP(B0[0], B0[1]);
        if (tail > 1) STEP(B0[2], B0[3]);
        if (tail > 2) STEP(B0[4], B0[5]);
        RENORM();
    }

    // store column lane8: element (j, i=lane8) at [i*8 + j]
    float* outp = logM + (size_t)grp * SLOT + lane8 * 8;
    #pragma unroll
    for (int j = 0; j < NS; ++j)
        outp[j] = fmaxf(__logf(p[j]), NEG1) + s;

    #undef LOADB
    #undef STEP
    #undef RENORM
}

// ---------------- Kernel B: gold + tree combine ----------------
__global__ __launch_bounds__(256) void crf_combineB(
    const float* __restrict__ feats,
    const float* __restrict__ trans,
    const int*   __restrict__ tags,
    const int*   __restrict__ lengths,
    const float* __restrict__ logM,
    float* __restrict__ perb,
    int T, int L)
{
    __shared__ float s_trans[81];
    __shared__ float s_mat[CHUNKS * 64];
    __shared__ float s_buf[(CHUNKS / 2) * 64];
    __shared__ float s_gold[4];
    __shared__ float s_alpha0[8];

    const int tid = threadIdx.x;
    const int b   = blockIdx.x;
    const int len = lengths[b];
    const float* fbase = feats + (size_t)b * T * KD;
    const int*   tg    = tags  + (size_t)b * T;

    if (tid < 81) s_trans[tid] = trans[tid];
    __syncthreads();

    // ---- gold score (data-parallel, 8 steps/thread) ----
    {
        int per = (T >> 8) > 0 ? (T >> 8) : 1;
        int t0  = tid * per;
        float g = 0.f;
        if (t0 < len) {
            int te   = min(t0 + per, len);
            int prev = (t0 == 0) ? START_TAG : tg[t0 - 1];
            for (int k = 0; k < per; ++k) {
                int t   = t0 + k;
                int tc  = min(t, te - 1);
                int cur = tg[tc];
                float v = s_trans[cur * KD + prev] + fbase[(size_t)tc * KD + cur];
                g += (t < te) ? v : 0.f;
                prev = cur;
            }
            if (len - 1 >= t0 && len - 1 < t0 + per)
                g += s_trans[STOP_TAG * KD + tg[len - 1]];
        }
        #pragma unroll
        for (int off = 32; off > 0; off >>= 1) g += __shfl_xor(g, off, 64);
        if ((tid & 63) == 0) s_gold[tid >> 6] = g;
    }

    if (tid < 8)
        s_alpha0[tid] = (tid < NS) ? (s_trans[tid * KD + START_TAG] + fbase[tid]) : NEG1;

    // ---- load chunk matrices (identity for inactive chunks) ----
    for (int idx = tid; idx < CHUNKS * SLOT; idx += 256) {
        int c = idx / SLOT, k = idx - c * SLOT;
        bool act = (c == 0) ? (len > 1) : (c * L < len);
        float v;
        if (act) v = logM[(size_t)(b * CHUNKS + c) * SLOT + k];
        else     v = ((k >> 3) == (k & 7)) ? 0.f : NEG1;
        s_mat[c * 64 + k] = v;
    }
    __syncthreads();

    // ---- tree fold: 5 rounds of 7x7 log-matmuls, 4 engines ----
    const int  e    = tid >> 6;
    const int  lane = tid & 63;
    const int  j    = lane % 7;
    const int  i    = lane / 7;
    const bool actl = lane < 49;

    #define PRODROUND(SRC, DST, P) do {                                         \
        for (int p_ = e; p_ < (P); p_ += 4) {                                   \
            const float* Lb = (SRC) + (2 * p_ + 1) * 64;                        \
            const float* Rb = (SRC) + (2 * p_) * 64;                            \
            if (actl) {                                                         \
                float tv[NS];                                                   \
                tv[0] = Lb[j] + Rb[i * 8];                                      \
                float tm = tv[0];                                               \
                _Pragma("unroll")                                               \
                for (int k = 1; k < NS; ++k) {                                  \
                    tv[k] = Lb[k * 8 + j] + Rb[i * 8 + k];                      \
                    tm = fmaxf(tm, tv[k]);                                      \
                }                                                               \
                float sum = 0.f;                                                \
                _Pragma("unroll")                                               \
                for (int k = 0; k < NS; ++k) sum += __expf(tv[k] - tm);         \
                (DST)[p_ * 64 + i * 8 + j] = tm + __logf(sum);                  \
            }                                                                   \
        }                                                                       \
        __syncthreads();                                                        \
    } while (0)

    PRODROUND(s_mat, s_buf, 16);
    PRODROUND(s_buf, s_mat, 8);
    PRODROUND(s_mat, s_buf, 4);
    PRODROUND(s_buf, s_mat, 2);
    PRODROUND(s_mat, s_buf, 1);
    #undef PRODROUND
    // final matrix in s_buf[0..63]

    if (tid < 8) {
        const bool isrow = (tid < NS);
        const int  jj    = isrow ? tid : 0;
        float tv[NS];
        tv[0] = s_buf[jj] + s_alpha0[0];
        float tm = tv[0];
        #pragma unroll
        for (int i2 = 1; i2 < NS; ++i2) {
            tv[i2] = s_buf[i2 * 8 + jj] + s_alpha0[i2];
            tm = fmaxf(tm, tv[i2]);
        }
        float sum = 0.f;
        #pragma unroll
        for (int i2 = 0; i2 < NS; ++i2) sum += __expf(tv[i2] - tm);
        float af = tm + __logf(sum);

        float term = isrow ? (af + s_trans[STOP_TAG * KD + tid]) : NEG1;
        float tm2 = term;
        #pragma unroll
        for (int off = 4; off > 0; off >>= 1) tm2 = fmaxf(tm2, __shfl_xor(tm2, off, 8));
        float ee = isrow ? __expf(term - tm2) : 0.f;
        #pragma unroll
        for (int off = 4; off > 0; off >>= 1) ee += __shfl_xor(ee, off, 8);

        if (tid == 0) {
            float fwd = tm2 + __logf(ee);
            perb[b] = fwd - (s_gold[0] + s_gold[1] + s_gold[2] + s_gold[3]);
        }
    }
}

// ---------------- Kernel C: mean reduce ----------------
__global__ __launch_bounds__(256) void crf_reduceC(
    const float* __restrict__ perb, float* __restrict__ out, int B)
{
    __shared__ float sd[256];
    float s = 0.f;
    for (int i = threadIdx.x; i < B; i += 256) s += perb[i];
    sd[threadIdx.x] = s;
    __syncthreads();
    for (int st = 128; st > 0; st >>= 1) {
        if (threadIdx.x < st) sd[threadIdx.x] += sd[threadIdx.x + st];
        __syncthreads();
    }
    if (threadIdx.x == 0) out[0] = sd[0] / (float)B;
}

extern "C" void kernel_launch(void* const* d_in, const int* in_sizes, int n_in,
                              void* d_out, int out_size, void* d_ws, size_t ws_size,
                              hipStream_t stream) {
    const float* feats   = (const float*)d_in[0];
    const float* trans   = (const float*)d_in[1];
    const int*   tags    = (const int*)d_in[2];
    const int*   lengths = (const int*)d_in[3];

    int B = in_sizes[3];
    int T = in_sizes[2] / B;
    int L = (T + CHUNKS - 1) / CHUNKS;   // 64 for T=2048

    float* logM = (float*)d_ws;                          // B*CHUNKS*SLOT floats
    float* perb = logM + (size_t)B * CHUNKS * SLOT;      // B floats

    crf_chunkA<<<(B * CHUNKS * 8) / 64, 64, 0, stream>>>(
        feats, trans, lengths, logM, T, L);
    crf_combineB<<<B, 256, 0, stream>>>(
        feats, trans, tags, lengths, logM, perb, T, L);
    crf_reduceC<<<1, 256, 0, stream>>>(perb, (float*)d_out, B);
}